// Round 4
// baseline (597.331 us; speedup 1.0000x reference)
//
#include <hip/hip_runtime.h>
#include <hip/hip_bf16.h>

#define T_SEQ   512
#define H_DIM   128
#define N3H     384
#define HS      136   // h row stride (ushort): 272B -> banks 4m, conflict-free b128
#define XS      72    // x row stride (ushort): 144B -> banks 4m

typedef float f32x4 __attribute__((ext_vector_type(4)));
typedef float f32x4u __attribute__((ext_vector_type(4), aligned(4)));
typedef __bf16 bf16x8 __attribute__((ext_vector_type(8)));
typedef unsigned short us8 __attribute__((ext_vector_type(8)));
typedef unsigned short us4 __attribute__((ext_vector_type(4)));

static __device__ __forceinline__ unsigned short f2bf(float f) {
    unsigned int u = __builtin_bit_cast(unsigned int, f);
    u += 0x7FFFu + ((u >> 16) & 1u);
    return (unsigned short)(u >> 16);
}

// LDS-only barrier: does not drain vmcnt (prefetch loads stay in flight).
static __device__ __forceinline__ void lds_barrier() {
    asm volatile("" ::: "memory");
    __builtin_amdgcn_s_waitcnt(0xC07F);   // lgkmcnt(0), vmcnt/expcnt max
    __builtin_amdgcn_s_barrier();
    asm volatile("" ::: "memory");
}

static __device__ __forceinline__ bf16x8 ld8(const unsigned short* p) {
    return __builtin_bit_cast(bf16x8, *(const us8*)p);
}

// 32 blocks x 16 batch rows x 256 threads (4 waves, 1/SIMD).
// Wave w owns 6 N-tiles {w, w+4 | 8+w, 12+w | 16+w, 20+w} = z/r/hh for
// h-col sets [16w,16w+16) and [64+16w, 64+16w+16) -> gates wave-local.
__global__ __launch_bounds__(256, 1) void gru_fused(
    const float* __restrict__ inputs, const float* __restrict__ Wx,
    const float* __restrict__ Wh, const float* __restrict__ bias,
    const float* __restrict__ W_state, const float* __restrict__ w1,
    const float* __restrict__ b1, const float* __restrict__ gamma,
    const float* __restrict__ beta, const float* __restrict__ mean,
    const float* __restrict__ var, const float* __restrict__ w2,
    const float* __restrict__ b2, float* __restrict__ out)
{
    __shared__ __attribute__((aligned(16))) unsigned short hb[2][16 * HS];
    __shared__ __attribute__((aligned(16))) unsigned short xb[2][16 * XS];
    __shared__ float hf[16][H_DIM + 1];

    const int tid  = threadIdx.x;
    const int w    = tid >> 6;      // wave 0..3
    const int lane = tid & 63;
    const int m    = lane & 15;
    const int q    = lane >> 4;
    const int b0   = blockIdx.x * 16;

    // ---- 6 weight tile-columns per wave, B-fragments in registers ----
    bf16x8 whB[6][4];
    bf16x8 wxB[6][2];
    float brec[6], bin[6];
#pragma unroll
    for (int g = 0; g < 6; ++g) {
        const int tile = (g < 2) ? (w + 4 * g)
                       : (g < 4) ? (8 + w + 4 * (g - 2))
                                 : (16 + w + 4 * (g - 4));
        const int col = tile * 16 + m;
#pragma unroll
        for (int k = 0; k < 4; ++k) {
            us8 tmp;
#pragma unroll
            for (int j = 0; j < 8; ++j) tmp[j] = f2bf(Wh[(32 * k + 8 * q + j) * N3H + col]);
            whB[g][k] = __builtin_bit_cast(bf16x8, tmp);
        }
#pragma unroll
        for (int k = 0; k < 2; ++k) {
            us8 tmp;
#pragma unroll
            for (int j = 0; j < 8; ++j) tmp[j] = f2bf(Wx[(32 * k + 8 * q + j) * N3H + col]);
            wxB[g][k] = __builtin_bit_cast(bf16x8, tmp);
        }
        bin[g]  = bias[col];
        brec[g] = bias[N3H + col];
    }

    // loop-invariant LDS offsets
    int hro[4], xro[2];
#pragma unroll
    for (int k = 0; k < 4; ++k) hro[k] = m * HS + 32 * k + 8 * q;
#pragma unroll
    for (int k = 0; k < 2; ++k) xro[k] = m * XS + 32 * k + 8 * q;
    const int hw_base = (4 * q) * HS + 16 * w + m;   // + i*HS + 64*j

    // staging: 256 threads, one float4 each (row sr, cols 4sc..4sc+3)
    const int sr = tid >> 4, sc = tid & 15;
    const int xwoff = sr * XS + sc * 4;
    const float* xsrc = inputs + ((size_t)(b0 + sr) * T_SEQ) * 65 + sc * 4;

    auto xpack = [&](f32x4u v) -> us4 {
        us4 r; r[0] = f2bf(v[0]); r[1] = f2bf(v[1]); r[2] = f2bf(v[2]); r[3] = f2bf(v[3]);
        return r;
    };

    // zero h(0)
    {
        unsigned int* p = (unsigned int*)hb[0];
        for (int i = tid; i < 16 * HS / 2; i += 256) p[i] = 0;
    }
    // stage x(0), x(1)
    {
        f32x4u v0 = *(const f32x4u*)(xsrc + 0 * 65);
        f32x4u v1 = *(const f32x4u*)(xsrc + 1 * 65);
        *(us4*)&xb[0][xwoff] = xpack(v0);
        *(us4*)&xb[1][xwoff] = xpack(v1);
    }
    lds_barrier();

    // xw(0)
    f32x4 xw_cur[6];
    {
        bf16x8 xa[2];
#pragma unroll
        for (int k = 0; k < 2; ++k) xa[k] = ld8(&xb[0][xro[k]]);
#pragma unroll
        for (int g = 0; g < 6; ++g) {
            f32x4 acc = { bin[g], bin[g], bin[g], bin[g] };
            acc = __builtin_amdgcn_mfma_f32_16x16x32_bf16(xa[0], wxB[g][0], acc, 0, 0, 0);
            acc = __builtin_amdgcn_mfma_f32_16x16x32_bf16(xa[1], wxB[g][1], acc, 0, 0, 0);
            xw_cur[g] = acc;
        }
    }

    f32x4u pf0 = {}, pf1 = {};
    pf0 = *(const f32x4u*)(xsrc + 2 * 65);   // x(2)

    f32x4 hreg[2] = { { 0.f, 0.f, 0.f, 0.f }, { 0.f, 0.f, 0.f, 0.f } };

    const float K1 = -1.4426950408889634f;   // -1/ln2
    const float K2 = -2.8853900817779268f;   // -2/ln2

    auto step = [&](int t, f32x4u& pfLoad, f32x4u& pfUse,
                    const unsigned short* hcur, unsigned short* hnxt,
                    const unsigned short* xnxt, unsigned short* xwr) {
        if (t <= T_SEQ - 4) pfLoad = *(const f32x4u*)(xsrc + (t + 3) * 65);

        lds_barrier();

        // rec(t) = h(t) @ Wh + b_rec  (two 2-MFMA chains per tile, 12-way ILP)
        bf16x8 ha[4];
#pragma unroll
        for (int k = 0; k < 4; ++k) ha[k] = ld8(&hcur[hro[k]]);
        f32x4 racc[6];
#pragma unroll
        for (int g = 0; g < 6; ++g) {
            f32x4 a1 = { brec[g], brec[g], brec[g], brec[g] };
            a1 = __builtin_amdgcn_mfma_f32_16x16x32_bf16(ha[0], whB[g][0], a1, 0, 0, 0);
            a1 = __builtin_amdgcn_mfma_f32_16x16x32_bf16(ha[1], whB[g][1], a1, 0, 0, 0);
            f32x4 a2 = { 0.f, 0.f, 0.f, 0.f };
            a2 = __builtin_amdgcn_mfma_f32_16x16x32_bf16(ha[2], whB[g][2], a2, 0, 0, 0);
            a2 = __builtin_amdgcn_mfma_f32_16x16x32_bf16(ha[3], whB[g][3], a2, 0, 0, 0);
            racc[g] = a1 + a2;
        }

        // xw(t+1) (independent of h)
        f32x4 xw_next[6];
        if (t < T_SEQ - 1) {
            bf16x8 xa[2];
#pragma unroll
            for (int k = 0; k < 2; ++k) xa[k] = ld8(&xnxt[xro[k]]);
#pragma unroll
            for (int g = 0; g < 6; ++g) {
                f32x4 acc = { bin[g], bin[g], bin[g], bin[g] };
                acc = __builtin_amdgcn_mfma_f32_16x16x32_bf16(xa[0], wxB[g][0], acc, 0, 0, 0);
                acc = __builtin_amdgcn_mfma_f32_16x16x32_bf16(xa[1], wxB[g][1], acc, 0, 0, 0);
                xw_next[g] = acc;
            }
        }

        // gates: col sets j=0 (16w+m), j=1 (64+16w+m); rows 4q+i
#pragma unroll
        for (int j = 0; j < 2; ++j) {
            f32x4 hnew;
#pragma unroll
            for (int i = 0; i < 4; ++i) {
                const float az = K1 * (xw_cur[0 + j][i] + racc[0 + j][i]);
                const float ar = K1 * (xw_cur[2 + j][i] + racc[2 + j][i]);
                const float ea = __builtin_amdgcn_exp2f(az);
                const float eb = __builtin_amdgcn_exp2f(ar);
                const float Pa = 1.0f + ea, Pb = 1.0f + eb;
                const float D  = __builtin_amdgcn_rcpf(Pa * Pb);
                const float z  = Pb * D;
                const float r  = Pa * D;
                float u = xw_cur[4 + j][i] + r * racc[4 + j][i];
                u = fminf(fmaxf(u, -15.0f), 15.0f);
                const float ec = __builtin_amdgcn_exp2f(K2 * u);
                const float T  = (1.0f - ec) * __builtin_amdgcn_rcpf(1.0f + ec);
                hnew[i] = T + z * (hreg[j][i] - T);
            }
            hreg[j] = hnew;
#pragma unroll
            for (int i = 0; i < 4; ++i)
                hnxt[hw_base + i * HS + 64 * j] = f2bf(hnew[i]);
        }

        // stage x(t+2) at end of step: vmcnt window spans the whole step
        if (t <= T_SEQ - 3) *(us4*)&xwr[xwoff] = xpack(pfUse);

        if (t < T_SEQ - 1) {
#pragma unroll
            for (int g = 0; g < 6; ++g) xw_cur[g] = xw_next[g];
        }
    };

    for (int t = 0; t < T_SEQ; t += 2) {
        step(t,     pf1, pf0, hb[0], hb[1], xb[1], xb[0]);
        step(t + 1, pf0, pf1, hb[1], hb[0], xb[0], xb[1]);
    }

    // ---- fused tail: +W_state, w1/ReLU/BN, w2 (block-local 16 rows) ----
#pragma unroll
    for (int j = 0; j < 2; ++j)
#pragma unroll
        for (int i = 0; i < 4; ++i)
            hf[4 * q + i][16 * w + 64 * j + m] = hreg[j][i];
    __syncthreads();

    const int ro = tid >> 4;
    {
        const float sf = inputs[((size_t)(b0 + ro) * T_SEQ + (T_SEQ - 1)) * 65 + 64];
        int si = (int)sf;
        si = si < 0 ? 0 : (si > 2 ? 2 : si);
        const int c0 = (tid & 15) * 8;
#pragma unroll
        for (int c = 0; c < 8; ++c)
            hf[ro][c0 + c] += W_state[si * H_DIM + c0 + c];
    }
    __syncthreads();

    {
        const int j0 = (tid & 15) * 4;
        f32x4 acc = *(const f32x4*)(b1 + j0);
        for (int k = 0; k < H_DIM; ++k) {
            const float hv = hf[ro][k];
            const f32x4 wv = *(const f32x4*)(w1 + k * 64 + j0);
#pragma unroll
            for (int ii = 0; ii < 4; ++ii) acc[ii] = fmaf(hv, wv[ii], acc[ii]);
        }
        const f32x4 mv = *(const f32x4*)(mean + j0);
        const f32x4 vv = *(const f32x4*)(var + j0);
        const f32x4 gv = *(const f32x4*)(gamma + j0);
        const f32x4 bv = *(const f32x4*)(beta + j0);
        const f32x4 w2v = *(const f32x4*)(w2 + j0);
        float v = 0.0f;
#pragma unroll
        for (int ii = 0; ii < 4; ++ii) {
            float a = fmaxf(acc[ii], 0.0f);
            a = (a - mv[ii]) * rsqrtf(vv[ii] + 1e-3f) * gv[ii] + bv[ii];
            v = fmaf(a, w2v[ii], v);
        }
        v += __shfl_down(v, 8);
        v += __shfl_down(v, 4);
        v += __shfl_down(v, 2);
        v += __shfl_down(v, 1);
        if ((tid & 15) == 0) out[b0 + ro] = v + b2[0];
    }
}

extern "C" void kernel_launch(void* const* d_in, const int* in_sizes, int n_in,
                              void* d_out, int out_size, void* d_ws, size_t ws_size,
                              hipStream_t stream) {
    (void)in_sizes; (void)n_in; (void)out_size; (void)d_ws; (void)ws_size;
    const float* inputs  = (const float*)d_in[0];
    const float* Wx      = (const float*)d_in[1];
    const float* Wh      = (const float*)d_in[2];
    const float* bias    = (const float*)d_in[3];
    const float* W_state = (const float*)d_in[4];
    const float* w1      = (const float*)d_in[5];
    const float* b1      = (const float*)d_in[6];
    const float* gamma   = (const float*)d_in[7];
    const float* beta    = (const float*)d_in[8];
    const float* mean    = (const float*)d_in[9];
    const float* var     = (const float*)d_in[10];
    const float* w2      = (const float*)d_in[11];
    const float* b2      = (const float*)d_in[12];
    float* out = (float*)d_out;

    gru_fused<<<32, 256, 0, stream>>>(inputs, Wx, Wh, bias, W_state, w1, b1,
                                      gamma, beta, mean, var, w2, b2, out);
}

// Round 5
// 500.044 us; speedup vs baseline: 1.1946x; 1.1946x over previous
//
#include <hip/hip_runtime.h>
#include <hip/hip_bf16.h>

#define T_SEQ   512
#define H_DIM   128
#define N3H     384
#define HS      136   // h row stride (ushort): 272B; A-frag b128 reads conflict-free
#define XS      72    // x row stride (ushort): 144B

typedef float f32x4 __attribute__((ext_vector_type(4)));
typedef float f32x2 __attribute__((ext_vector_type(2)));
typedef float f32x4u __attribute__((ext_vector_type(4), aligned(4)));
typedef __bf16 bf16x8 __attribute__((ext_vector_type(8)));
typedef unsigned short us8 __attribute__((ext_vector_type(8)));
typedef unsigned short us4 __attribute__((ext_vector_type(4)));

static __device__ __forceinline__ unsigned short f2bf(float f) {
    unsigned int u = __builtin_bit_cast(unsigned int, f);
    u += 0x7FFFu + ((u >> 16) & 1u);
    return (unsigned short)(u >> 16);
}

// LDS-only barrier: lgkmcnt(0) but vmcnt untouched -> global prefetch loads
// stay in flight across the barrier.
static __device__ __forceinline__ void lds_barrier() {
    asm volatile("" ::: "memory");
    __builtin_amdgcn_s_waitcnt(0xC07F);   // lgkmcnt(0), vmcnt/expcnt max
    __builtin_amdgcn_s_barrier();
    asm volatile("" ::: "memory");
}

static __device__ __forceinline__ bf16x8 ld8(const unsigned short* p) {
    return __builtin_bit_cast(bf16x8, *(const us8*)p);
}

// 32 blocks x 16 batch rows x 512 threads (8 waves, 2/SIMD).
// Wave w owns N-tiles {w, 8+w, 16+w}: z/r/hh for cols [16w,16w+16) wave-local.
__global__ __launch_bounds__(512, 1) void gru_fused(
    const float* __restrict__ inputs, const float* __restrict__ Wx,
    const float* __restrict__ Wh, const float* __restrict__ bias,
    const float* __restrict__ W_state, const float* __restrict__ w1,
    const float* __restrict__ b1, const float* __restrict__ gamma,
    const float* __restrict__ beta, const float* __restrict__ mean,
    const float* __restrict__ var, const float* __restrict__ w2,
    const float* __restrict__ b2, float* __restrict__ out)
{
    __shared__ __attribute__((aligned(16))) unsigned short hb[2][16 * HS];
    __shared__ __attribute__((aligned(16))) unsigned short xb[2][16 * XS];
    __shared__ float hf[16][H_DIM + 1];

    const int tid  = threadIdx.x;
    const int w    = tid >> 6;      // wave 0..7
    const int lane = tid & 63;
    const int m    = lane & 15;
    const int q    = lane >> 4;
    const int b0   = blockIdx.x * 16;

    // ---- weight B-fragments in registers for all 512 steps ----
    bf16x8 whB[3][4];
    bf16x8 wxB[3][2];
    float brec[3], bin[3];
#pragma unroll
    for (int g = 0; g < 3; ++g) {
        const int col = (8 * g + w) * 16 + m;   // tile w / 8+w / 16+w
#pragma unroll
        for (int k = 0; k < 4; ++k) {
            us8 tmp;
#pragma unroll
            for (int j = 0; j < 8; ++j) tmp[j] = f2bf(Wh[(32 * k + 8 * q + j) * N3H + col]);
            whB[g][k] = __builtin_bit_cast(bf16x8, tmp);
        }
#pragma unroll
        for (int k = 0; k < 2; ++k) {
            us8 tmp;
#pragma unroll
            for (int j = 0; j < 8; ++j) tmp[j] = f2bf(Wx[(32 * k + 8 * q + j) * N3H + col]);
            wxB[g][k] = __builtin_bit_cast(bf16x8, tmp);
        }
        bin[g]  = bias[col];
        brec[g] = bias[N3H + col];
    }

    // loop-invariant LDS offsets (ushort units)
    int hro[4], xro[2];
#pragma unroll
    for (int k = 0; k < 4; ++k) hro[k] = m * HS + 32 * k + 8 * q;
#pragma unroll
    for (int k = 0; k < 2; ++k) xro[k] = m * XS + 32 * k + 8 * q;
    const int hw_base = (4 * q) * HS + 16 * w + m;   // + i*HS

    // staging: threads 0..255 load one float4 (row sr, cols 4sc..4sc+3)
    const int sr = tid >> 4, sc = tid & 15;
    const int xwoff = sr * XS + sc * 4;
    const float* xsrc = inputs + ((size_t)(b0 + sr) * T_SEQ) * 65 + sc * 4;

    auto xpack = [&](f32x4u v) -> us4 {
        us4 r; r[0] = f2bf(v[0]); r[1] = f2bf(v[1]); r[2] = f2bf(v[2]); r[3] = f2bf(v[3]);
        return r;
    };

    // zero h(0)
    {
        unsigned int* p = (unsigned int*)hb[0];
        for (int i = tid; i < 16 * HS / 2; i += 512) p[i] = 0;
    }
    // stage x(0), x(1)
    if (tid < 256) {
        f32x4u v0 = *(const f32x4u*)(xsrc + 0 * 65);
        f32x4u v1 = *(const f32x4u*)(xsrc + 1 * 65);
        *(us4*)&xb[0][xwoff] = xpack(v0);
        *(us4*)&xb[1][xwoff] = xpack(v1);
    }
    lds_barrier();

    // xw(0)
    f32x4 xwA[3], xwB[3];
    {
        bf16x8 xa[2];
#pragma unroll
        for (int k = 0; k < 2; ++k) xa[k] = ld8(&xb[0][xro[k]]);
#pragma unroll
        for (int g = 0; g < 3; ++g) {
            f32x4 acc = { bin[g], bin[g], bin[g], bin[g] };
            acc = __builtin_amdgcn_mfma_f32_16x16x32_bf16(xa[0], wxB[g][0], acc, 0, 0, 0);
            acc = __builtin_amdgcn_mfma_f32_16x16x32_bf16(xa[1], wxB[g][1], acc, 0, 0, 0);
            xwA[g] = acc;
        }
    }

    f32x4u pf0 = {}, pf1 = {};
    if (tid < 256) pf0 = *(const f32x4u*)(xsrc + 2 * 65);   // x(2)

    f32x4 hreg = { 0.f, 0.f, 0.f, 0.f };

    const float K1 = -1.4426950408889634f;   // -1/ln2
    const float K2 = -2.8853900817779268f;   // -2/ln2

    auto step = [&](int t, f32x4* xw_cur, f32x4* xw_next,
                    f32x4u& pfLoad, f32x4u& pfUse,
                    const unsigned short* hcur, unsigned short* hnxt,
                    const unsigned short* xnxt, unsigned short* xwr) {
        // global prefetch x(t+3) — spans the barrier (vmcnt not drained)
        if (tid < 256 && t <= T_SEQ - 4) pfLoad = *(const f32x4u*)(xsrc + (t + 3) * 65);

        lds_barrier();

        // rec(t) = h(t) @ Wh + b_rec  (two 2-deep MFMA chains per gate)
        bf16x8 ha[4];
#pragma unroll
        for (int k = 0; k < 4; ++k) ha[k] = ld8(&hcur[hro[k]]);
        f32x4 racc[3];
#pragma unroll
        for (int g = 0; g < 3; ++g) {
            f32x4 a1 = { brec[g], brec[g], brec[g], brec[g] };
            a1 = __builtin_amdgcn_mfma_f32_16x16x32_bf16(ha[0], whB[g][0], a1, 0, 0, 0);
            a1 = __builtin_amdgcn_mfma_f32_16x16x32_bf16(ha[1], whB[g][1], a1, 0, 0, 0);
            f32x4 a2 = { 0.f, 0.f, 0.f, 0.f };
            a2 = __builtin_amdgcn_mfma_f32_16x16x32_bf16(ha[2], whB[g][2], a2, 0, 0, 0);
            a2 = __builtin_amdgcn_mfma_f32_16x16x32_bf16(ha[3], whB[g][3], a2, 0, 0, 0);
            racc[g] = a1 + a2;
        }

        // xw(t+1) — independent of h, overlaps the rec chain
        if (t < T_SEQ - 1) {
            bf16x8 xa[2];
#pragma unroll
            for (int k = 0; k < 2; ++k) xa[k] = ld8(&xnxt[xro[k]]);
#pragma unroll
            for (int g = 0; g < 3; ++g) {
                f32x4 acc = { bin[g], bin[g], bin[g], bin[g] };
                acc = __builtin_amdgcn_mfma_f32_16x16x32_bf16(xa[0], wxB[g][0], acc, 0, 0, 0);
                acc = __builtin_amdgcn_mfma_f32_16x16x32_bf16(xa[1], wxB[g][1], acc, 0, 0, 0);
                xw_next[g] = acc;
            }
        }

        // gates (5 transcendentals/elem: 3 exp2 + 2 rcp, z/r share one rcp)
        f32x4 hnew;
#pragma unroll
        for (int i = 0; i < 4; ++i) {
            const float az = K1 * (xw_cur[0][i] + racc[0][i]);
            const float ar = K1 * (xw_cur[1][i] + racc[1][i]);
            const float ea = __builtin_amdgcn_exp2f(az);
            const float eb = __builtin_amdgcn_exp2f(ar);
            const float Pa = 1.0f + ea, Pb = 1.0f + eb;
            const float D  = __builtin_amdgcn_rcpf(Pa * Pb);
            const float z  = Pb * D;           // sigmoid(pre_z)
            const float r  = Pa * D;           // sigmoid(pre_r)
            float u = xw_cur[2][i] + r * racc[2][i];
            u = fminf(fmaxf(u, -15.0f), 15.0f);
            const float ec = __builtin_amdgcn_exp2f(K2 * u);
            const float T  = (1.0f - ec) * __builtin_amdgcn_rcpf(1.0f + ec);
            hnew[i] = T + z * (hreg[i] - T);
        }
        hreg = hnew;

        // write h(t+1)
#pragma unroll
        for (int i = 0; i < 4; ++i) hnxt[hw_base + i * HS] = f2bf(hnew[i]);

        // stage x(t+2) into LDS at end of step (off the h critical path)
        if (tid < 256 && t <= T_SEQ - 3) *(us4*)&xwr[xwoff] = xpack(pfUse);
    };

    for (int t = 0; t < T_SEQ; t += 2) {
        step(t,     xwA, xwB, pf1, pf0, hb[0], hb[1], xb[1], xb[0]);
        step(t + 1, xwB, xwA, pf0, pf1, hb[1], hb[0], xb[0], xb[1]);
    }

    // ---- fused tail: +W_state, w1/ReLU/BN, w2 ----
#pragma unroll
    for (int i = 0; i < 4; ++i)
        hf[4 * q + i][16 * w + m] = hreg[i];
    __syncthreads();

    {   // hf[row][c..c+3] += W_state[si(row)][c..c+3]; 512 thr x 4 elems
        const int row = tid >> 5;
        const int c0  = (tid & 31) * 4;
        const float sf = inputs[((size_t)(b0 + row) * T_SEQ + (T_SEQ - 1)) * 65 + 64];
        int si = (int)sf;
        si = si < 0 ? 0 : (si > 2 ? 2 : si);
#pragma unroll
        for (int c = 0; c < 4; ++c)
            hf[row][c0 + c] += W_state[si * H_DIM + c0 + c];
    }
    __syncthreads();

    {   // per thread: row = tid>>5, two output cols jj, jj+1
        const int row = tid >> 5;
        const int jj  = (tid & 31) * 2;
        f32x2 acc = { b1[jj], b1[jj + 1] };
        for (int k = 0; k < H_DIM; ++k) {
            const float hv = hf[row][k];
            const f32x2 wv = *(const f32x2*)(w1 + k * 64 + jj);
            acc[0] = fmaf(hv, wv[0], acc[0]);
            acc[1] = fmaf(hv, wv[1], acc[1]);
        }
        float v = 0.0f;
#pragma unroll
        for (int ii = 0; ii < 2; ++ii) {
            const int j = jj + ii;
            float a = fmaxf(acc[ii], 0.0f);
            a = (a - mean[j]) * rsqrtf(var[j] + 1e-3f) * gamma[j] + beta[j];
            v = fmaf(a, w2[j], v);
        }
        v += __shfl_down(v, 16);
        v += __shfl_down(v, 8);
        v += __shfl_down(v, 4);
        v += __shfl_down(v, 2);
        v += __shfl_down(v, 1);
        if ((tid & 31) == 0) out[b0 + row] = v + b2[0];
    }
}

extern "C" void kernel_launch(void* const* d_in, const int* in_sizes, int n_in,
                              void* d_out, int out_size, void* d_ws, size_t ws_size,
                              hipStream_t stream) {
    (void)in_sizes; (void)n_in; (void)out_size; (void)d_ws; (void)ws_size;
    const float* inputs  = (const float*)d_in[0];
    const float* Wx      = (const float*)d_in[1];
    const float* Wh      = (const float*)d_in[2];
    const float* bias    = (const float*)d_in[3];
    const float* W_state = (const float*)d_in[4];
    const float* w1      = (const float*)d_in[5];
    const float* b1      = (const float*)d_in[6];
    const float* gamma   = (const float*)d_in[7];
    const float* beta    = (const float*)d_in[8];
    const float* mean    = (const float*)d_in[9];
    const float* var     = (const float*)d_in[10];
    const float* w2      = (const float*)d_in[11];
    const float* b2      = (const float*)d_in[12];
    float* out = (float*)d_out;

    gru_fused<<<32, 512, 0, stream>>>(inputs, Wx, Wh, bias, W_state, w1, b1,
                                      gamma, beta, mean, var, w2, b2, out);
}